// Round 1
// baseline (119.493 us; speedup 1.0000x reference)
//
#include <hip/hip_runtime.h>

// Tiny MLP: Linear(2,15)+SiLU -> Linear(15,15)+SiLU -> Linear(15,15)+SiLU -> Linear(15,1)+Sigmoid
// N = 2^21 rows, fp32 everywhere. VALU-bound (no fp32 MFMA on CDNA4).
//
// Strategy: all weights staged to LDS (padded stride 16 -> vectorizable rows,
// wave-uniform addresses -> broadcast reads, no bank conflicts). 2 rows per
// thread so every weight read feeds 2 FMAs. Full unroll.

#define LOG2E 1.4426950408889634f

__device__ __forceinline__ float fast_sigmoid(float x) {
    // 1 / (1 + e^-x); v_exp_f32 + v_rcp_f32, ~1ulp each
    return __builtin_amdgcn_rcpf(1.0f + __expf(-x));
}

__global__ __launch_bounds__(256) void mlp_kernel(
    const float* __restrict__ x,
    const float* __restrict__ W1, const float* __restrict__ b1,
    const float* __restrict__ W2, const float* __restrict__ b2,
    const float* __restrict__ W3, const float* __restrict__ b3,
    const float* __restrict__ W4, const float* __restrict__ b4,
    float* __restrict__ out, int N)
{
    __shared__ float sW1[2][16];
    __shared__ float sB1[16];
    __shared__ float sW2[15][16];
    __shared__ float sB2[16];
    __shared__ float sW3[15][16];
    __shared__ float sB3[16];
    __shared__ float sW4[16];
    __shared__ float sB4;

    const int t = threadIdx.x;

    // ---- cooperative weight staging (pad col 15 with zeros) ----
    if (t < 32) {
        int r = t >> 4, c = t & 15;
        sW1[r][c] = (c < 15) ? W1[r * 15 + c] : 0.0f;
    }
    for (int idx = t; idx < 15 * 16; idx += 256) {
        int r = idx >> 4, c = idx & 15;
        sW2[r][c] = (c < 15) ? W2[r * 15 + c] : 0.0f;
        sW3[r][c] = (c < 15) ? W3[r * 15 + c] : 0.0f;
    }
    if (t < 16) {
        sB1[t] = (t < 15) ? b1[t] : 0.0f;
        sB2[t] = (t < 15) ? b2[t] : 0.0f;
        sB3[t] = (t < 15) ? b3[t] : 0.0f;
        sW4[t] = (t < 15) ? W4[t] : 0.0f;
    }
    if (t == 0) sB4 = b4[0];
    __syncthreads();

    // ---- 2 rows per thread ----
    const int base = (blockIdx.x * 256 + t) * 2;   // first row index
    if (base >= N) return;

    // x is [N,2]: float4 = (x0_r0, x1_r0, x0_r1, x1_r1)
    const float4 xv = *reinterpret_cast<const float4*>(x + (size_t)base * 2);

    float hA[2][16];
    float acc[2][16];

    // ---- layer 1: 2 -> 15, SiLU ----
    #pragma unroll
    for (int j = 0; j < 16; ++j) {
        float w0 = sW1[0][j], w1 = sW1[1][j], bb = sB1[j];
        float a0 = fmaf(xv.x, w0, fmaf(xv.y, w1, bb));
        float a1 = fmaf(xv.z, w0, fmaf(xv.w, w1, bb));
        hA[0][j] = a0 * fast_sigmoid(a0);
        hA[1][j] = a1 * fast_sigmoid(a1);
    }

    // ---- layer 2: 15 -> 15, SiLU ----
    #pragma unroll
    for (int j = 0; j < 16; ++j) { float bb = sB2[j]; acc[0][j] = bb; acc[1][j] = bb; }
    #pragma unroll
    for (int i = 0; i < 15; ++i) {
        float h0 = hA[0][i], h1 = hA[1][i];
        #pragma unroll
        for (int j = 0; j < 16; ++j) {
            float w = sW2[i][j];
            acc[0][j] = fmaf(h0, w, acc[0][j]);
            acc[1][j] = fmaf(h1, w, acc[1][j]);
        }
    }
    #pragma unroll
    for (int j = 0; j < 16; ++j) {
        hA[0][j] = acc[0][j] * fast_sigmoid(acc[0][j]);
        hA[1][j] = acc[1][j] * fast_sigmoid(acc[1][j]);
    }

    // ---- layer 3: 15 -> 15, SiLU ----
    #pragma unroll
    for (int j = 0; j < 16; ++j) { float bb = sB3[j]; acc[0][j] = bb; acc[1][j] = bb; }
    #pragma unroll
    for (int i = 0; i < 15; ++i) {
        float h0 = hA[0][i], h1 = hA[1][i];
        #pragma unroll
        for (int j = 0; j < 16; ++j) {
            float w = sW3[i][j];
            acc[0][j] = fmaf(h0, w, acc[0][j]);
            acc[1][j] = fmaf(h1, w, acc[1][j]);
        }
    }
    #pragma unroll
    for (int j = 0; j < 16; ++j) {
        hA[0][j] = acc[0][j] * fast_sigmoid(acc[0][j]);
        hA[1][j] = acc[1][j] * fast_sigmoid(acc[1][j]);
    }

    // ---- layer 4: 15 -> 1, sigmoid ----
    float o0 = sB4, o1 = sB4;
    #pragma unroll
    for (int i = 0; i < 15; ++i) {
        float w = sW4[i];
        o0 = fmaf(hA[0][i], w, o0);
        o1 = fmaf(hA[1][i], w, o1);
    }

    float2 res;
    res.x = fast_sigmoid(o0);
    res.y = fast_sigmoid(o1);
    *reinterpret_cast<float2*>(out + base) = res;
}

extern "C" void kernel_launch(void* const* d_in, const int* in_sizes, int n_in,
                              void* d_out, int out_size, void* d_ws, size_t ws_size,
                              hipStream_t stream) {
    const float* x  = (const float*)d_in[0];
    const float* W1 = (const float*)d_in[1];
    const float* b1 = (const float*)d_in[2];
    const float* W2 = (const float*)d_in[3];
    const float* b2 = (const float*)d_in[4];
    const float* W3 = (const float*)d_in[5];
    const float* b3 = (const float*)d_in[6];
    const float* W4 = (const float*)d_in[7];
    const float* b4 = (const float*)d_in[8];
    float* out = (float*)d_out;

    const int N = in_sizes[0] / 2;            // rows
    const int rows_per_block = 256 * 2;
    const int grid = (N + rows_per_block - 1) / rows_per_block;

    mlp_kernel<<<grid, 256, 0, stream>>>(x, W1, b1, W2, b2, W3, b3, W4, b4, out, N);
}

// Round 2
// 112.979 us; speedup vs baseline: 1.0577x; 1.0577x over previous
//
#include <hip/hip_runtime.h>

// Tiny MLP 2->15->15->15->1 (SiLU x3, sigmoid), N=2^21 rows, fp32 in/out.
//
// Round-2 strategy: all three H-dim matmuls on the MFMA pipe
// (v_mfma_f32_16x16x16_f16), activations kept "feature-major":
//   D = A*B with A = W^T (constant per-lane fragment), B = H[k][sample].
// For the 16x16x16 shape, D-layout (row=quad*4+r, col=lane&15) is
// structurally identical to B-layout (k=quad*4+i, n=lane&15), so
// bias+SiLU applied elementwise in-register chains layers with ZERO
// cross-lane data movement and ZERO LDS. VALU now only does layer-1
// (K=2), SiLU, and f32->f16 converts; MFMA does the 480 MACs/row.

using half4  = __attribute__((ext_vector_type(4))) _Float16;
using floatx4 = __attribute__((ext_vector_type(4))) float;

__device__ __forceinline__ float fast_sigmoid(float x) {
    // v_mul(log2e) + v_exp_f32 + v_add + v_rcp_f32
    return __builtin_amdgcn_rcpf(1.0f + __expf(-x));
}
__device__ __forceinline__ float silu(float x) {
    return x * fast_sigmoid(x);
}

__global__ __launch_bounds__(256) void mlp_mfma(
    const float* __restrict__ x,
    const float* __restrict__ W1, const float* __restrict__ b1,
    const float* __restrict__ W2, const float* __restrict__ b2,
    const float* __restrict__ W3, const float* __restrict__ b3,
    const float* __restrict__ W4, const float* __restrict__ b4,
    float* __restrict__ out, int N)
{
    const int lane = threadIdx.x & 63;
    const int col  = lane & 15;   // sample slot (B/D col) and A-row m
    const int quad = lane >> 4;   // k-group

    // ---- constant per-lane fragments (loaded once, L2-cached) ----
    half4 A2, A3, A4;             // weights as A-operand: A[m][k] = W[k][m]
    float w10[4], w11[4], vb1[4]; // layer-1 weight columns for this lane's 4 k's
    float vb2[4], vb3[4];         // bias for the D rows this lane holds
    #pragma unroll
    for (int i = 0; i < 4; ++i) {
        const int k   = quad * 4 + i;   // input-feature index (A k / B k)
        const int m   = col;            // output-feature row of A
        const bool kin = (k < 15);
        A2[i] = (_Float16)((kin && m < 15) ? W2[k * 15 + m] : 0.0f);
        A3[i] = (_Float16)((kin && m < 15) ? W3[k * 15 + m] : 0.0f);
        A4[i] = (_Float16)((kin && m == 0) ? W4[k]          : 0.0f);
        w10[i] = kin ? W1[0 * 15 + k] : 0.0f;
        w11[i] = kin ? W1[1 * 15 + k] : 0.0f;
        vb1[i] = kin ? b1[k] : 0.0f;
        const int mq = quad * 4 + i;    // D row held in reg i
        vb2[i] = (mq < 15) ? b2[mq] : 0.0f;
        vb3[i] = (mq < 15) ? b3[mq] : 0.0f;
    }
    const float b4s = b4[0];
    const floatx4 zero = {0.f, 0.f, 0.f, 0.f};

    // ---- grid-stride over tile-pairs (2 x 16 samples) for ILP ----
    const int wave   = (blockIdx.x * blockDim.x + threadIdx.x) >> 6;
    const int nwaves = (gridDim.x * blockDim.x) >> 6;
    const int npairs = N >> 5;    // N / 32

    for (int p = wave; p < npairs; p += nwaves) {
        const int base0 = p * 32;
        const int base1 = base0 + 16;
        const float2 xv0 = *reinterpret_cast<const float2*>(x + 2 * (base0 + col));
        const float2 xv1 = *reinterpret_cast<const float2*>(x + 2 * (base1 + col));

        // layer 1: 2 -> 15, SiLU, build B fragments (feature-major)
        half4 B0, B1v;
        #pragma unroll
        for (int i = 0; i < 4; ++i) {
            const float a0 = fmaf(xv0.x, w10[i], fmaf(xv0.y, w11[i], vb1[i]));
            const float a1 = fmaf(xv1.x, w10[i], fmaf(xv1.y, w11[i], vb1[i]));
            B0[i]  = (_Float16)silu(a0);
            B1v[i] = (_Float16)silu(a1);
        }

        // layer 2 on MFMA pipe
        floatx4 d0 = __builtin_amdgcn_mfma_f32_16x16x16f16(A2, B0,  zero, 0, 0, 0);
        floatx4 d1 = __builtin_amdgcn_mfma_f32_16x16x16f16(A2, B1v, zero, 0, 0, 0);
        #pragma unroll
        for (int r = 0; r < 4; ++r) {
            B0[r]  = (_Float16)silu(d0[r] + vb2[r]);
            B1v[r] = (_Float16)silu(d1[r] + vb2[r]);
        }

        // layer 3
        d0 = __builtin_amdgcn_mfma_f32_16x16x16f16(A3, B0,  zero, 0, 0, 0);
        d1 = __builtin_amdgcn_mfma_f32_16x16x16f16(A3, B1v, zero, 0, 0, 0);
        #pragma unroll
        for (int r = 0; r < 4; ++r) {
            B0[r]  = (_Float16)silu(d0[r] + vb3[r]);
            B1v[r] = (_Float16)silu(d1[r] + vb3[r]);
        }

        // layer 4: 15 -> 1 (only row 0 of D is real)
        d0 = __builtin_amdgcn_mfma_f32_16x16x16f16(A4, B0,  zero, 0, 0, 0);
        d1 = __builtin_amdgcn_mfma_f32_16x16x16f16(A4, B1v, zero, 0, 0, 0);

        const float o0 = fast_sigmoid(d0[0] + b4s);
        const float o1 = fast_sigmoid(d1[0] + b4s);
        if (lane < 16) {            // quad 0 holds D row 0
            out[base0 + lane] = o0;
            out[base1 + lane] = o1;
        }
    }
}

extern "C" void kernel_launch(void* const* d_in, const int* in_sizes, int n_in,
                              void* d_out, int out_size, void* d_ws, size_t ws_size,
                              hipStream_t stream) {
    const float* x  = (const float*)d_in[0];
    const float* W1 = (const float*)d_in[1];
    const float* b1 = (const float*)d_in[2];
    const float* W2 = (const float*)d_in[3];
    const float* b2 = (const float*)d_in[4];
    const float* W3 = (const float*)d_in[5];
    const float* b3 = (const float*)d_in[6];
    const float* W4 = (const float*)d_in[7];
    const float* b4 = (const float*)d_in[8];
    float* out = (float*)d_out;

    const int N = in_sizes[0] / 2;   // rows
    const int blocks = 2048;         // 8 blocks/CU, 8 waves/SIMD
    mlp_mfma<<<blocks, 256, 0, stream>>>(x, W1, b1, W2, b2, W3, b3, W4, b4, out, N);
}

// Round 4
// 111.751 us; speedup vs baseline: 1.0693x; 1.0110x over previous
//
#include <hip/hip_runtime.h>

// Tiny MLP 2->15->15->15->1 (SiLU x3, sigmoid), N=2^21 rows, fp32 in/out.
//
// Round-4 (= round-3 with compile fix): matmuls on the MFMA pipe
// (v_mfma_f32_16x16x16_f16, feature-major chaining: D-layout == B-layout,
// zero cross-lane moves, zero LDS). VALU stream minimized:
//  - packed fp32 (v_pk_fma/add/mul via float2 ext-vectors)
//  - v_cvt_pkrtz_f16_f32 converts+packs two f32->half2 in one instr
// The 52 transcendentals per 32-sample pair (exp+rcp per SiLU) are the
// semantic floor and should now dominate the VALU pipe.

using half4   = __attribute__((ext_vector_type(4))) _Float16;
using half2v  = __attribute__((ext_vector_type(2))) _Float16;
using fp16x2  = __attribute__((ext_vector_type(2))) __fp16;   // cvt_pkrtz return type
using floatx4 = __attribute__((ext_vector_type(4))) float;
using v2f     = __attribute__((ext_vector_type(2))) float;

__device__ __forceinline__ v2f sigmoid2(v2f x) {
    // per element: exp(-x) (v_exp_f32 w/ folded log2e mul) + pk_add + v_rcp
    v2f e;
    e[0] = __expf(-x[0]);
    e[1] = __expf(-x[1]);
    v2f den = e + 1.0f;
    v2f r;
    r[0] = __builtin_amdgcn_rcpf(den[0]);
    r[1] = __builtin_amdgcn_rcpf(den[1]);
    return r;
}

__device__ __forceinline__ half2v silu2h(v2f x) {
    v2f s = x * sigmoid2(x);                          // v_pk_mul_f32
    fp16x2 p = __builtin_amdgcn_cvt_pkrtz(s[0], s[1]); // v_cvt_pkrtz_f16_f32
    return __builtin_bit_cast(half2v, p);
}

__global__ __launch_bounds__(256) void mlp_mfma(
    const float* __restrict__ x,
    const float* __restrict__ W1, const float* __restrict__ b1,
    const float* __restrict__ W2, const float* __restrict__ b2,
    const float* __restrict__ W3, const float* __restrict__ b3,
    const float* __restrict__ W4, const float* __restrict__ b4,
    float* __restrict__ out, int N)
{
    const int lane = threadIdx.x & 63;
    const int col  = lane & 15;   // sample slot (B/D col) and A-row m
    const int quad = lane >> 4;   // k-group

    // ---- constant per-lane fragments (loaded once, L2-cached) ----
    half4 A2, A3, A4;                 // A[m][k] = W[k][m]
    v2f w10p[2], w11p[2], vb1p[2];    // layer-1 packed across i-pairs
    v2f vb2p[2], vb3p[2];             // bias packed across D-row reg pairs
    #pragma unroll
    for (int i = 0; i < 4; ++i) {
        const int k    = quad * 4 + i;   // input-feature index
        const int m    = col;            // output-feature (A row)
        const bool kin = (k < 15);
        A2[i] = (_Float16)((kin && m < 15) ? W2[k * 15 + m] : 0.0f);
        A3[i] = (_Float16)((kin && m < 15) ? W3[k * 15 + m] : 0.0f);
        A4[i] = (_Float16)((kin && m == 0) ? W4[k]          : 0.0f);
        w10p[i >> 1][i & 1] = kin ? W1[0 * 15 + k] : 0.0f;
        w11p[i >> 1][i & 1] = kin ? W1[1 * 15 + k] : 0.0f;
        vb1p[i >> 1][i & 1] = kin ? b1[k] : 0.0f;
        const int mq = quad * 4 + i;     // D row held in reg i
        vb2p[i >> 1][i & 1] = (mq < 15) ? b2[mq] : 0.0f;
        vb3p[i >> 1][i & 1] = (mq < 15) ? b3[mq] : 0.0f;
    }
    const float b4s = b4[0];
    const floatx4 zero = {0.f, 0.f, 0.f, 0.f};

    const int wave   = (blockIdx.x * blockDim.x + threadIdx.x) >> 6;
    const int nwaves = (gridDim.x * blockDim.x) >> 6;
    const int npairs = N >> 5;    // N / 32 (two 16-sample tiles per iter)

    for (int p = wave; p < npairs; p += nwaves) {
        const int base0 = p * 32;
        const int base1 = base0 + 16;
        const float2 xv0 = *reinterpret_cast<const float2*>(x + 2 * (base0 + col));
        const float2 xv1 = *reinterpret_cast<const float2*>(x + 2 * (base1 + col));

        // ---- layer 1: 2 -> 15, SiLU, build B fragments ----
        half4 B0, B1v;
        #pragma unroll
        for (int j = 0; j < 2; ++j) {         // j indexes reg pairs (i=2j,2j+1)
            v2f a0 = w10p[j] * xv0.x + (w11p[j] * xv0.y + vb1p[j]);
            v2f a1 = w10p[j] * xv1.x + (w11p[j] * xv1.y + vb1p[j]);
            half2v p0 = silu2h(a0);
            half2v p1 = silu2h(a1);
            B0[2*j]  = p0[0]; B0[2*j+1]  = p0[1];
            B1v[2*j] = p1[0]; B1v[2*j+1] = p1[1];
        }

        // ---- layer 2 (MFMA) + bias/SiLU epilogue ----
        floatx4 d0 = __builtin_amdgcn_mfma_f32_16x16x16f16(A2, B0,  zero, 0, 0, 0);
        floatx4 d1 = __builtin_amdgcn_mfma_f32_16x16x16f16(A2, B1v, zero, 0, 0, 0);
        #pragma unroll
        for (int j = 0; j < 2; ++j) {
            v2f t0 = (v2f){d0[2*j], d0[2*j+1]} + vb2p[j];
            v2f t1 = (v2f){d1[2*j], d1[2*j+1]} + vb2p[j];
            half2v p0 = silu2h(t0);
            half2v p1 = silu2h(t1);
            B0[2*j]  = p0[0]; B0[2*j+1]  = p0[1];
            B1v[2*j] = p1[0]; B1v[2*j+1] = p1[1];
        }

        // ---- layer 3 ----
        d0 = __builtin_amdgcn_mfma_f32_16x16x16f16(A3, B0,  zero, 0, 0, 0);
        d1 = __builtin_amdgcn_mfma_f32_16x16x16f16(A3, B1v, zero, 0, 0, 0);
        #pragma unroll
        for (int j = 0; j < 2; ++j) {
            v2f t0 = (v2f){d0[2*j], d0[2*j+1]} + vb3p[j];
            v2f t1 = (v2f){d1[2*j], d1[2*j+1]} + vb3p[j];
            half2v p0 = silu2h(t0);
            half2v p1 = silu2h(t1);
            B0[2*j]  = p0[0]; B0[2*j+1]  = p0[1];
            B1v[2*j] = p1[0]; B1v[2*j+1] = p1[1];
        }

        // ---- layer 4: 15 -> 1, sigmoid ----
        d0 = __builtin_amdgcn_mfma_f32_16x16x16f16(A4, B0,  zero, 0, 0, 0);
        d1 = __builtin_amdgcn_mfma_f32_16x16x16f16(A4, B1v, zero, 0, 0, 0);

        v2f o = (v2f){d0[0], d1[0]} + b4s;
        v2f s = sigmoid2(o);
        if (lane < 16) {           // quad 0 / reg 0 holds D row 0
            out[base0 + lane] = s[0];
            out[base1 + lane] = s[1];
        }
    }
}

extern "C" void kernel_launch(void* const* d_in, const int* in_sizes, int n_in,
                              void* d_out, int out_size, void* d_ws, size_t ws_size,
                              hipStream_t stream) {
    const float* x  = (const float*)d_in[0];
    const float* W1 = (const float*)d_in[1];
    const float* b1 = (const float*)d_in[2];
    const float* W2 = (const float*)d_in[3];
    const float* b2 = (const float*)d_in[4];
    const float* W3 = (const float*)d_in[5];
    const float* b3 = (const float*)d_in[6];
    const float* W4 = (const float*)d_in[7];
    const float* b4 = (const float*)d_in[8];
    float* out = (float*)d_out;

    const int N = in_sizes[0] / 2;   // rows
    const int blocks = 2048;         // 8 blocks/CU at 256 thr -> 32 waves/CU
    mlp_mfma<<<blocks, 256, 0, stream>>>(x, W1, b1, W2, b2, W3, b3, W4, b4, out, N);
}

// Round 5
// 108.886 us; speedup vs baseline: 1.0974x; 1.0263x over previous
//
#include <hip/hip_runtime.h>

// Tiny MLP 2->15->15->15->1 (SiLU x3, sigmoid), N=2^21 rows, fp32 in/out.
//
// Round-5: matmuls stay on the MFMA pipe (16x16x16 f16, feature-major
// chaining: D-layout == B-layout, zero cross-lane moves, zero LDS).
// New this round (attacking exposed latency + trans count):
//  - 4 tiles (64 samples) per grid-stride iteration -> 2x independent
//    dependency chains per wave
//  - software prefetch of next iteration's x loads
//  - paired-reciprocal: 1/a = b*rcp(ab) -> 25% fewer transcendentals
//    (2 exp + 1 rcp per 2-wide SiLU instead of 2+2)

using half4   = __attribute__((ext_vector_type(4))) _Float16;
using half2v  = __attribute__((ext_vector_type(2))) _Float16;
using fp16x2  = __attribute__((ext_vector_type(2))) __fp16;
using floatx4 = __attribute__((ext_vector_type(4))) float;
using v2f     = __attribute__((ext_vector_type(2))) float;

__device__ __forceinline__ v2f sigmoid2(v2f x) {
    // den = 1 + exp(-x); paired reciprocal: 1 rcp for 2 lanesx2 elements
    v2f den;
    den[0] = 1.0f + __expf(-x[0]);
    den[1] = 1.0f + __expf(-x[1]);
    const float r = __builtin_amdgcn_rcpf(den[0] * den[1]);
    return (v2f){den[1] * r, den[0] * r};
}

__device__ __forceinline__ half2v silu2h(v2f x) {
    v2f s = x * sigmoid2(x);                            // v_pk_mul_f32
    fp16x2 p = __builtin_amdgcn_cvt_pkrtz(s[0], s[1]);  // one cvt+pack
    return __builtin_bit_cast(half2v, p);
}

__global__ __launch_bounds__(256, 4) void mlp_mfma(
    const float* __restrict__ x,
    const float* __restrict__ W1, const float* __restrict__ b1,
    const float* __restrict__ W2, const float* __restrict__ b2,
    const float* __restrict__ W3, const float* __restrict__ b3,
    const float* __restrict__ W4, const float* __restrict__ b4,
    float* __restrict__ out, int N)
{
    const int lane = threadIdx.x & 63;
    const int col  = lane & 15;   // sample slot (B/D col) and A-row m
    const int quad = lane >> 4;   // k-group

    // ---- constant per-lane fragments (loaded once, L2-cached) ----
    half4 A2, A3, A4;                 // A[m][k] = W[k][m]
    v2f w10p[2], w11p[2], vb1p[2];    // layer-1 packed across i-pairs
    v2f vb2p[2], vb3p[2];             // bias packed across D-row reg pairs
    #pragma unroll
    for (int i = 0; i < 4; ++i) {
        const int k    = quad * 4 + i;   // input-feature index
        const int m    = col;            // output-feature (A row)
        const bool kin = (k < 15);
        A2[i] = (_Float16)((kin && m < 15) ? W2[k * 15 + m] : 0.0f);
        A3[i] = (_Float16)((kin && m < 15) ? W3[k * 15 + m] : 0.0f);
        A4[i] = (_Float16)((kin && m == 0) ? W4[k]          : 0.0f);
        w10p[i >> 1][i & 1] = kin ? W1[0 * 15 + k] : 0.0f;
        w11p[i >> 1][i & 1] = kin ? W1[1 * 15 + k] : 0.0f;
        vb1p[i >> 1][i & 1] = kin ? b1[k] : 0.0f;
        const int mq = quad * 4 + i;     // D row held in reg i
        vb2p[i >> 1][i & 1] = (mq < 15) ? b2[mq] : 0.0f;
        vb3p[i >> 1][i & 1] = (mq < 15) ? b3[mq] : 0.0f;
    }
    const float b4s = b4[0];
    const floatx4 zero = {0.f, 0.f, 0.f, 0.f};

    const int wave   = (blockIdx.x * blockDim.x + threadIdx.x) >> 6;
    const int nwaves = (gridDim.x * blockDim.x) >> 6;
    const int nquads = N >> 6;          // 64 samples per iteration

    if (wave >= nquads) return;

    // ---- prime the pipeline: load iteration-0 x ----
    float2 xc[4];
    #pragma unroll
    for (int t = 0; t < 4; ++t)
        xc[t] = *reinterpret_cast<const float2*>(x + 2 * (wave * 64 + t * 16 + col));

    for (int q = wave; q < nquads; ) {
        const int qn   = q + nwaves;
        const int qp   = (qn < nquads) ? qn : q;   // safe re-load on last iter
        // ---- prefetch next iteration's x (hides HBM latency) ----
        float2 xn[4];
        #pragma unroll
        for (int t = 0; t < 4; ++t)
            xn[t] = *reinterpret_cast<const float2*>(x + 2 * (qp * 64 + t * 16 + col));

        // ---- layer 1: 2 -> 15, SiLU, build 4 B fragments ----
        half4 B[4];
        #pragma unroll
        for (int t = 0; t < 4; ++t) {
            #pragma unroll
            for (int j = 0; j < 2; ++j) {
                v2f a = w10p[j] * xc[t].x + (w11p[j] * xc[t].y + vb1p[j]);
                half2v p = silu2h(a);
                B[t][2*j] = p[0]; B[t][2*j+1] = p[1];
            }
        }

        // ---- layer 2 (MFMA) + bias/SiLU ----
        floatx4 d[4];
        #pragma unroll
        for (int t = 0; t < 4; ++t)
            d[t] = __builtin_amdgcn_mfma_f32_16x16x16f16(A2, B[t], zero, 0, 0, 0);
        #pragma unroll
        for (int t = 0; t < 4; ++t) {
            #pragma unroll
            for (int j = 0; j < 2; ++j) {
                v2f tt = (v2f){d[t][2*j], d[t][2*j+1]} + vb2p[j];
                half2v p = silu2h(tt);
                B[t][2*j] = p[0]; B[t][2*j+1] = p[1];
            }
        }

        // ---- layer 3 ----
        #pragma unroll
        for (int t = 0; t < 4; ++t)
            d[t] = __builtin_amdgcn_mfma_f32_16x16x16f16(A3, B[t], zero, 0, 0, 0);
        #pragma unroll
        for (int t = 0; t < 4; ++t) {
            #pragma unroll
            for (int j = 0; j < 2; ++j) {
                v2f tt = (v2f){d[t][2*j], d[t][2*j+1]} + vb3p[j];
                half2v p = silu2h(tt);
                B[t][2*j] = p[0]; B[t][2*j+1] = p[1];
            }
        }

        // ---- layer 4: 15 -> 1, sigmoid ----
        #pragma unroll
        for (int t = 0; t < 4; ++t)
            d[t] = __builtin_amdgcn_mfma_f32_16x16x16f16(A4, B[t], zero, 0, 0, 0);

        v2f o01 = (v2f){d[0][0], d[1][0]} + b4s;
        v2f o23 = (v2f){d[2][0], d[3][0]} + b4s;
        v2f s01 = sigmoid2(o01);
        v2f s23 = sigmoid2(o23);
        if (lane < 16) {   // quad 0 / reg 0 holds D row 0
            out[q * 64 +  0 + lane] = s01[0];
            out[q * 64 + 16 + lane] = s01[1];
            out[q * 64 + 32 + lane] = s23[0];
            out[q * 64 + 48 + lane] = s23[1];
        }

        q = qn;
        #pragma unroll
        for (int t = 0; t < 4; ++t) xc[t] = xn[t];
    }
}

extern "C" void kernel_launch(void* const* d_in, const int* in_sizes, int n_in,
                              void* d_out, int out_size, void* d_ws, size_t ws_size,
                              hipStream_t stream) {
    const float* x  = (const float*)d_in[0];
    const float* W1 = (const float*)d_in[1];
    const float* b1 = (const float*)d_in[2];
    const float* W2 = (const float*)d_in[3];
    const float* b2 = (const float*)d_in[4];
    const float* W3 = (const float*)d_in[5];
    const float* b3 = (const float*)d_in[6];
    const float* W4 = (const float*)d_in[7];
    const float* b4 = (const float*)d_in[8];
    float* out = (float*)d_out;

    const int N = in_sizes[0] / 2;   // rows
    const int blocks = 2048;
    mlp_mfma<<<blocks, 256, 0, stream>>>(x, W1, b1, W2, b2, W3, b3, W4, b4, out, N);
}